// Round 13
// baseline (862.655 us; speedup 1.0000x reference)
//
#include <hip/hip_runtime.h>
#include <math.h>

typedef unsigned short u16;
typedef unsigned int   u32;
typedef __attribute__((ext_vector_type(8))) short short8;
typedef __attribute__((ext_vector_type(4))) float f32x4;

typedef const void __attribute__((address_space(1))) gvoid_t;
typedef void       __attribute__((address_space(3))) svoid_t;

__device__ __forceinline__ void gload_lds16(const void* g, void* l){
    __builtin_amdgcn_global_load_lds((gvoid_t*)g, (svoid_t*)l, 16, 0, 0);
}

__device__ __forceinline__ float gelu_f(float x){
    return 0.5f * x * (1.0f + erff(x * 0.70710678118654752f));
}
__device__ __forceinline__ u16 f2b(float x){
    union{float f; u32 u;} v; v.f = x;
    u32 r = (v.u + 0x7fffu + ((v.u >> 16) & 1u)) >> 16;
    return (u16)r;
}
__device__ __forceinline__ float b2f(u16 h){
    union{u32 u; float f;} v; v.u = ((u32)h) << 16; return v.f;
}

// ===================== bf16 MFMA GEMM (frozen from round 12) =====================
template<int EPI, int GUARD, int CGUARD>
__global__ __launch_bounds__(256)
void gemm_bf16(const u16* __restrict__ A, int lda,
               const u16* __restrict__ B, int ldb,
               void* __restrict__ Cv, int ldc,
               const float* __restrict__ bias,
               const float* __restrict__ rowv,
               void* __restrict__ resid, int ldr,
               int Mrows, int Ncols, int K, int splitK,
               long sA, long sB, long sC, long sRV,
               float scale)
{
    const int bz = blockIdx.z;
    const int b  = bz / splitK, kc = bz % splitK;
    A += (long)b * sA;  B += (long)b * sB;
    const float* rv = (EPI == 3) ? rowv + (long)b * sRV : nullptr;

    __shared__ u16 SMEM[32768];
    __shared__ float xds[128];
    u16* const As0 = SMEM;
    u16* const Bs0 = SMEM + 8192;
    u16* const As1 = SMEM + 16384;
    u16* const Bs1 = SMEM + 24576;

    const int tid = threadIdx.x;

    const int gx  = gridDim.x;
    const int nwg = gx * gridDim.y;
    const int L   = blockIdx.y * gx + blockIdx.x;
    const int q8  = nwg >> 3, r8 = nwg & 7;
    const int xc  = L & 7,   i8 = L >> 3;
    const int nid = (xc < r8 ? xc * (q8 + 1) : r8 * (q8 + 1) + (xc - r8) * q8) + i8;
    const int row0 = (nid / gx) * 128, col0 = (nid % gx) * 128;

    f32x4 acc[4][4] = {};
    float sqacc[4] = {0.f, 0.f, 0.f, 0.f};

    const int l  = tid & 63, w4 = tid >> 6;
    const int wr = w4 >> 1, wc = w4 & 1;
    const int g  = l >> 4,  mr = l & 15;

    const int kLen   = K / splitK;
    const int kStart = kc * kLen;
    const int nt     = kLen / 64;

    const int m0   = w4 * 8 + (l >> 3);
    const int k8s  = (l & 7) ^ (m0 & 7);
    const int lBase = w4 * 512 + l * 8;
    const u16* gA0 = A + (long)(row0 + m0) * lda + kStart + k8s * 8;
    const u16* gB0 = B + (long)(col0 + m0) * ldb + kStart + k8s * 8;

    int aOff[4], bOff[4], sl[2];
    #pragma unroll
    for (int i = 0; i < 4; i++){
        aOff[i] = (wr * 64 + i * 16 + mr) * 64;
        bOff[i] = (wc * 64 + i * 16 + mr) * 64;
    }
    #pragma unroll
    for (int kk = 0; kk < 2; kk++)
        sl[kk] = (((kk * 4 + g) ^ (mr & 7)) & 7) * 8;

#define STAGE(AS, BS, KOFF)                                             \
    {                                                                   \
        _Pragma("unroll")                                               \
        for (int q = 0; q < 4; q++){                                    \
            gload_lds16(gA0 + (long)q * 32 * lda + (KOFF), &(AS)[lBase + q * 2048]); \
            gload_lds16(gB0 + (long)q * 32 * ldb + (KOFF), &(BS)[lBase + q * 2048]); \
        }                                                               \
    }

#define COMPUTE(AS, BS)                                                 \
    {                                                                   \
        short8 af[2][4], bfr[2][4];                                     \
        _Pragma("unroll")                                               \
        for (int kk = 0; kk < 2; kk++){                                 \
            _Pragma("unroll")                                           \
            for (int i = 0; i < 4; i++){                                \
                af[kk][i]  = *(const short8*)&(AS)[aOff[i] + sl[kk]];   \
                bfr[kk][i] = *(const short8*)&(BS)[bOff[i] + sl[kk]];   \
            }                                                           \
        }                                                               \
        if (EPI == 10){                                                 \
            _Pragma("unroll")                                           \
            for (int kk = 0; kk < 2; kk++)                              \
                _Pragma("unroll")                                       \
                for (int i = 0; i < 4; i++)                             \
                    _Pragma("unroll")                                   \
                    for (int e = 0; e < 8; e++){                        \
                        float f_ = b2f((u16)af[kk][i][e]);              \
                        sqacc[i] += f_ * f_;                            \
                    }                                                   \
        }                                                               \
        _Pragma("unroll")                                               \
        for (int kk = 0; kk < 2; kk++)                                  \
            _Pragma("unroll")                                           \
            for (int i = 0; i < 4; i++)                                 \
                _Pragma("unroll")                                       \
                for (int j = 0; j < 4; j++)                             \
                    acc[i][j] = __builtin_amdgcn_mfma_f32_16x16x32_bf16(af[kk][i], bfr[kk][j], acc[i][j], 0, 0, 0); \
    }

    STAGE(As0, Bs0, 0);

    for (int t = 0; t < nt; ){
        __syncthreads();
        if (t + 1 < nt) STAGE(As1, Bs1, (t + 1) * 64);
        COMPUTE(As0, Bs0);
        t++;
        if (t >= nt) break;
        __syncthreads();
        if (t + 1 < nt) STAGE(As0, Bs0, (t + 1) * 64);
        COMPUTE(As1, Bs1);
        t++;
    }
#undef STAGE
#undef COMPUTE

    if (EPI == 10){
        #pragma unroll
        for (int i = 0; i < 4; i++){
            float s = sqacc[i];
            s += __shfl_xor(s, 16);
            s += __shfl_xor(s, 32);
            if (l < 16) xds[wr * 64 + i * 16 + l] = 0.5f * s;
        }
    }
    __syncthreads();

    float* Cf = (float*)Cv + (EPI == 8 ? (long)bz : (long)b) * sC;
    u16*   Cb = (u16*)Cv   + (EPI == 10 ? 0L : (long)b * sC);

    if (EPI == 10 && bz == 0){
        #pragma unroll
        for (int i = 0; i < 4; i++){
            #pragma unroll
            for (int j = 0; j < 4; j++){
                const int col = col0 + wc * 64 + j * 16 + mr;
                if (CGUARD && col >= Ncols) continue;
                const int lrow = wr * 64 + i * 16 + g * 4;
                u16 pk[4];
                #pragma unroll
                for (int r = 0; r < 4; r++)
                    pk[r] = f2b(expf(acc[i][j][r] - xds[lrow + r]) * scale);
                *(ushort4*)&Cb[(long)col * ldc + row0 + lrow] = *(ushort4*)pk;
            }
        }
        return;
    }

    constexpr bool OUTF32 = (EPI == 4 || EPI == 8 || EPI == 9);
    float* const Sf = (float*)SMEM;
    #pragma unroll
    for (int i = 0; i < 4; i++){
        #pragma unroll
        for (int j = 0; j < 4; j++){
            const int cl = wc * 64 + j * 16 + mr;
            const float bv = (EPI == 0 || EPI == 1 || EPI == 4 || EPI == 9)
                           ? bias[col0 + cl] : 0.f;
            #pragma unroll
            for (int r = 0; r < 4; r++){
                const int rl = wr * 64 + i * 16 + g * 4 + r;
                float vv = acc[i][j][r];
                if      (EPI == 1)  vv = gelu_f(vv + bv);
                else if (EPI == 3)  vv = vv / (rv[row0 + rl] + 1e-8f);
                else if (EPI == 10) vv = expf(vv - xds[rl]) * scale;
                else                vv += bv;
                if (OUTF32) Sf[rl * 128 + cl] = vv;
                else        SMEM[rl * 128 + cl] = f2b(vv);
            }
        }
    }
    __syncthreads();

    if (OUTF32){
        #pragma unroll
        for (int s = 0; s < 16; s++){
            const int qi = s * 256 + tid;
            const int rl = qi >> 5, c4 = (qi & 31) << 2;
            const int row = row0 + rl, col = col0 + c4;
            if (GUARD && row >= Mrows) continue;
            if (CGUARD && col >= Ncols) continue;
            float4 v = *(float4*)&Sf[rl * 128 + c4];
            if (EPI == 4){
                float4 rr = *(const float4*)&((const float*)resid)[(long)row * ldr + col];
                v.x += rr.x; v.y += rr.y; v.z += rr.z; v.w += rr.w;
            } else if (EPI == 9){
                ushort4 rh = *(const ushort4*)&((const u16*)resid)[(long)row * ldr + col];
                v.x += b2f(rh.x); v.y += b2f(rh.y); v.z += b2f(rh.z); v.w += b2f(rh.w);
            }
            *(float4*)&Cf[(long)row * ldc + col] = v;
        }
    } else {
        u16* dst; long ld;
        if (EPI == 10){ dst = (u16*)resid; ld = ldr; }
        else          { dst = Cb;          ld = ldc; }
        #pragma unroll
        for (int s = 0; s < 8; s++){
            const int oi = s * 256 + tid;
            const int rl = oi >> 4, c8 = (oi & 15) << 3;
            const int row = row0 + rl, col = col0 + c8;
            if (GUARD && row >= Mrows) continue;
            if (CGUARD && col >= Ncols) continue;
            *(uint4*)&dst[(long)row * ld + col] = *(uint4*)&SMEM[rl * 128 + c8];
        }
    }
}

// ===================== fusedA: h1=GELU(a0@W1t+b1); x=h1@W2t+b2; xn=LN1(x) ============
// One block per 128-row panel. h1 kept in a 96KB swizzled LDS panel ([128][384],
// slice slot s of row m in each 64-k group holds k8 = s^(m&7) -- same scheme as
// the GEMM core, so phase-2 A-reads use the identical sl[] addressing).
// Phase 2 accumulates LN1 row stats (f32, pre-rounding) via shfl reduction;
// phase 3 re-reads the L2-hot x panel and writes xn.
__global__ __launch_bounds__(256)
void fusedA(const u16* __restrict__ a0,   // [Mc][768]
            const u16* __restrict__ w1t,  // [384][768]
            const float* __restrict__ b1,
            const u16* __restrict__ w2t,  // [384][384]
            const float* __restrict__ b2,
            const float* __restrict__ g1, const float* __restrict__ be1,
            u16* __restrict__ xb,         // [Mc][384] scratch
            u16* __restrict__ xnb)        // [Mc][384] out
{
    __shared__ u16 h1L[128 * 384];        // 96 KB
    __shared__ u16 Sa[8192];              // 16 KB
    __shared__ u16 Sb[8192];              // 16 KB
    __shared__ float sumP[128][2], sqP[128][2], muL[128], invL[128];

    const int tid = threadIdx.x;
    // T1 swizzle over 1-D grid
    const int nwg = gridDim.x;
    const int L = blockIdx.x;
    const int q8 = nwg >> 3, r8 = nwg & 7;
    const int xc = L & 7, i8 = L >> 3;
    const int nid = (xc < r8 ? xc * (q8 + 1) : r8 * (q8 + 1) + (xc - r8) * q8) + i8;
    const int row0 = nid * 128;

    const int l = tid & 63, w4 = tid >> 6;
    const int wr = w4 >> 1, wc = w4 & 1;
    const int g = l >> 4, mr = l & 15;

    const int m0 = w4 * 8 + (l >> 3);
    const int k8s = (l & 7) ^ (m0 & 7);
    const int lBase = w4 * 512 + l * 8;

    int aOff2[4], bOff[4], sl[2];
    #pragma unroll
    for (int i = 0; i < 4; i++){
        aOff2[i] = (wr * 64 + i * 16 + mr) * 384;
        bOff[i]  = (wc * 64 + i * 16 + mr) * 64;
    }
    #pragma unroll
    for (int kk = 0; kk < 2; kk++)
        sl[kk] = (((kk * 4 + g) ^ (mr & 7)) & 7) * 8;

    if (tid < 128){
        sumP[tid][0] = 0.f; sumP[tid][1] = 0.f;
        sqP[tid][0]  = 0.f; sqP[tid][1]  = 0.f;
    }

    const u16* gA1 = a0 + (long)(row0 + m0) * 768 + k8s * 8;

    // ---------- phase 1: h1 col-tiles (K=768) ----------
    for (int c = 0; c < 3; c++){
        const u16* gB1 = w1t + (long)(c * 128 + m0) * 768 + k8s * 8;
        f32x4 acc[4][4] = {};
        for (int t = 0; t < 12; t++){
            __syncthreads();
            #pragma unroll
            for (int q = 0; q < 4; q++){
                gload_lds16(gA1 + (long)q * 32 * 768 + t * 64, &Sa[lBase + q * 2048]);
                gload_lds16(gB1 + (long)q * 32 * 768 + t * 64, &Sb[lBase + q * 2048]);
            }
            __syncthreads();
            short8 af[2][4], bfr[2][4];
            #pragma unroll
            for (int kk = 0; kk < 2; kk++)
                #pragma unroll
                for (int i = 0; i < 4; i++){
                    af[kk][i]  = *(const short8*)&Sa[(wr * 64 + i * 16 + mr) * 64 + sl[kk]];
                    bfr[kk][i] = *(const short8*)&Sb[bOff[i] + sl[kk]];
                }
            #pragma unroll
            for (int kk = 0; kk < 2; kk++)
                #pragma unroll
                for (int i = 0; i < 4; i++)
                    #pragma unroll
                    for (int j = 0; j < 4; j++)
                        acc[i][j] = __builtin_amdgcn_mfma_f32_16x16x32_bf16(af[kk][i], bfr[kk][j], acc[i][j], 0, 0, 0);
        }
        // epilogue: GELU -> h1L (swizzled within each 64-k group)
        #pragma unroll
        for (int i = 0; i < 4; i++){
            #pragma unroll
            for (int j = 0; j < 4; j++){
                const int col = wc * 64 + j * 16 + mr;
                const int kglob = c * 128 + col;
                const float bv = b1[kglob];
                const int kt = kglob & ~63;
                const int k8 = (kglob >> 3) & 7;
                const int e  = kglob & 7;
                #pragma unroll
                for (int r = 0; r < 4; r++){
                    const int row = wr * 64 + i * 16 + g * 4 + r;
                    const float vv = gelu_f(acc[i][j][r] + bv);
                    h1L[row * 384 + kt + ((k8 ^ (row & 7)) << 3) + e] = f2b(vv);
                }
            }
        }
    }
    __syncthreads();   // h1L complete

    // ---------- phase 2: x col-tiles (K=384, A from h1L) ----------
    for (int c2 = 0; c2 < 3; c2++){
        const u16* gB2 = w2t + (long)(c2 * 128 + m0) * 384 + k8s * 8;
        f32x4 acc[4][4] = {};
        for (int t = 0; t < 6; t++){
            __syncthreads();
            #pragma unroll
            for (int q = 0; q < 4; q++)
                gload_lds16(gB2 + (long)q * 32 * 384 + t * 64, &Sb[lBase + q * 2048]);
            __syncthreads();
            short8 af[2][4], bfr[2][4];
            #pragma unroll
            for (int kk = 0; kk < 2; kk++)
                #pragma unroll
                for (int i = 0; i < 4; i++){
                    af[kk][i]  = *(const short8*)&h1L[aOff2[i] + t * 64 + sl[kk]];
                    bfr[kk][i] = *(const short8*)&Sb[bOff[i] + sl[kk]];
                }
            #pragma unroll
            for (int kk = 0; kk < 2; kk++)
                #pragma unroll
                for (int i = 0; i < 4; i++)
                    #pragma unroll
                    for (int j = 0; j < 4; j++)
                        acc[i][j] = __builtin_amdgcn_mfma_f32_16x16x32_bf16(af[kk][i], bfr[kk][j], acc[i][j], 0, 0, 0);
        }
        // epilogue: x = acc + b2 -> xb (scalar) ; LN stats (f32 pre-rounding)
        #pragma unroll
        for (int i = 0; i < 4; i++){
            #pragma unroll
            for (int r = 0; r < 4; r++){
                const int row = wr * 64 + i * 16 + g * 4 + r;
                float s1 = 0.f, s2 = 0.f;
                #pragma unroll
                for (int j = 0; j < 4; j++){
                    const int col = c2 * 128 + wc * 64 + j * 16 + mr;
                    const float vv = acc[i][j][r] + b2[col];
                    xb[(long)(row0 + row) * 384 + col] = f2b(vv);
                    s1 += vv; s2 += vv * vv;
                }
                #pragma unroll
                for (int off = 1; off < 16; off <<= 1){
                    s1 += __shfl_xor(s1, off);
                    s2 += __shfl_xor(s2, off);
                }
                if (mr == 0){
                    sumP[row][wc] += s1;
                    sqP[row][wc]  += s2;
                }
            }
        }
        __syncthreads();   // stats writes visible; Sb free for next c2
    }

    if (tid < 128){
        const float s = sumP[tid][0] + sumP[tid][1];
        const float q = sqP[tid][0] + sqP[tid][1];
        const float mu = s * (1.0f / 384.0f);
        const float var = q * (1.0f / 384.0f) - mu * mu;
        muL[tid] = mu;
        invL[tid] = rsqrtf(var + 1e-5f);
    }
    __syncthreads();

    // ---------- phase 3: xn = (x-mu)*inv*g + beta ----------
    for (int ro = 0; ro < 24; ro++){
        const int idx = ro * 256 + tid;          // 6144 chunks of 8
        const int row = idx / 48, c8 = (idx % 48) * 8;
        short8 v8 = *(const short8*)&xb[(long)(row0 + row) * 384 + c8];
        const float mu = muL[row], inv = invL[row];
        short8 o8;
        #pragma unroll
        for (int e = 0; e < 8; e++){
            const float xv = b2f((u16)v8[e]);
            o8[e] = (short)f2b((xv - mu) * inv * g1[c8 + e] + be1[c8 + e]);
        }
        *(short8*)&xnb[(long)(row0 + row) * 384 + c8] = o8;
    }
}

// bf16 strided transpose
__global__ __launch_bounds__(256)
void trb_kernel(const u16* __restrict__ in, long inStride, u16* __restrict__ out, long R)
{
    __shared__ u16 t[64][72];
    const long cb = (long)blockIdx.x * 64, rb = (long)blockIdx.y * 64;
    const int tl = threadIdx.x & 63, tw = threadIdx.x >> 6;
    #pragma unroll
    for (int i = 0; i < 16; i++){
        const int r = tw + i * 4;
        t[r][tl] = in[(rb + r) * inStride + cb + tl];
    }
    __syncthreads();
    #pragma unroll
    for (int i = 0; i < 16; i++){
        const int c = tw + i * 4;
        out[(cb + c) * R + rb + tl] = t[tl][c];
    }
}

__global__ __launch_bounds__(256)
void kred_kernel(const float* __restrict__ in, u16* __restrict__ out, long n)
{
    long idx = (long)blockIdx.x * 256 + threadIdx.x;
    if (idx >= n) return;
    const long b = idx / 73728, r = idx - b * 73728;
    const float* s = in + b * 7 * 73728L + r;
    float acc = 0.f;
    #pragma unroll
    for (int kc = 0; kc < 7; kc++) acc += s[kc * 73728L];
    out[idx] = f2b(acc);
}

// LayerNorm over D=384; input f32 (INF32=1) or bf16 (INF32=0); bf16 out.
template<int INF32>
__global__ __launch_bounds__(256)
void ln_kernel(const void* __restrict__ xv, u16* __restrict__ ob,
               const float* __restrict__ g, const float* __restrict__ bta)
{
    const int lane = threadIdx.x & 63;
    const long r = (long)blockIdx.x * 4 + (threadIdx.x >> 6);
    float v[6]; float s = 0.f;
    #pragma unroll
    for (int i = 0; i < 6; i++){
        const int c = lane + i * 64;
        v[i] = INF32 ? ((const float*)xv)[r * 384 + c]
                     : b2f(((const u16*)xv)[r * 384 + c]);
        s += v[i];
    }
    #pragma unroll
    for (int off = 32; off; off >>= 1) s += __shfl_xor(s, off);
    const float mu = s * (1.0f/384.0f);
    float q = 0.f;
    #pragma unroll
    for (int i = 0; i < 6; i++){ float d = v[i] - mu; q += d*d; }
    #pragma unroll
    for (int off = 32; off; off >>= 1) q += __shfl_xor(q, off);
    const float inv = rsqrtf(q * (1.0f/384.0f) + 1e-5f);
    #pragma unroll
    for (int i = 0; i < 6; i++){
        const int c = lane + i*64;
        ob[r * 384 + c] = f2b((v[i] - mu) * inv * g[c] + bta[c]);
    }
}

// Dn[r] = dot(qp_bf16[r,:192], kpsum[r/T,:192])
__global__ __launch_bounds__(256)
void dn_kernel(const u16* __restrict__ qp, const float* __restrict__ kpsum,
               float* __restrict__ Dn, int T)
{
    const int lane = threadIdx.x & 63;
    const long r = (long)blockIdx.x * 4 + (threadIdx.x >> 6);
    const int b = (int)(r / T);
    const u16* qr = qp + r * 192;
    const float* ks = kpsum + (long)b * 192;
    float s = 0.f;
    #pragma unroll
    for (int i = 0; i < 3; i++){ const int m = lane + i*64; s += b2f(qr[m]) * ks[m]; }
    #pragma unroll
    for (int off = 32; off; off >>= 1) s += __shfl_xor(s, off);
    if (lane == 0) Dn[r] = s;
}

// kpsum[bl][m] = sum_t kpT[m][bl*T + t]
__global__ __launch_bounds__(256)
void kpsum2_kernel(const u16* __restrict__ kpT, float* __restrict__ kpsum, long Mc, int T)
{
    const int lane = threadIdx.x & 63;
    const int gw = blockIdx.x * 4 + (threadIdx.x >> 6);
    const int m = gw % 192, bl = gw / 192;
    const u16* row = kpT + (long)m * Mc + (long)bl * T;
    float s = 0.f;
    for (int i = lane; i < T; i += 64) s += b2f(row[i]);
    #pragma unroll
    for (int off = 32; off; off >>= 1) s += __shfl_xor(s, off);
    if (lane == 0) kpsum[bl * 192 + m] = s;
}

__global__ __launch_bounds__(256)
void zero_kernel(float* __restrict__ p, long n)
{
    long i = (long)blockIdx.x * 256 + threadIdx.x;
    long stride = (long)gridDim.x * 256;
    for (; i < n; i += stride) p[i] = 0.f;
}

// concat(in1,in2) row-major -> bf16 [Mc][768]
__global__ __launch_bounds__(256)
void ca_kernel(const float* __restrict__ i1, const float* __restrict__ i2,
               u16* __restrict__ a0, long nquad)
{
    long idx = (long)blockIdx.x * 256 + threadIdx.x;
    if (idx >= nquad) return;
    const long r = idx / 192;
    const int  c0 = (int)(idx % 192) * 4;
    const float* src = (c0 < 384) ? &i1[r * 384 + c0] : &i2[r * 384 + (c0 - 384)];
    float4 v = *(const float4*)src;
    u32 w0 = (u32)f2b(v.x) | ((u32)f2b(v.y) << 16);
    u32 w1 = (u32)f2b(v.z) | ((u32)f2b(v.w) << 16);
    *(uint2*)&a0[r * 768 + c0] = make_uint2(w0, w1);
}

// wt[n*K + k] = bf16(w[k*N + n])
__global__ __launch_bounds__(256)
void wt_kernel(const float* __restrict__ w, u16* __restrict__ wt, int K, int N, long total)
{
    long idx = (long)blockIdx.x * 256 + threadIdx.x;
    if (idx >= total) return;
    const long n = idx / K, k = idx - n * K;
    wt[idx] = f2b(w[k * N + n]);
}

// flat f32 -> bf16
__global__ __launch_bounds__(256)
void cvt_kernel(const float* __restrict__ s, u16* __restrict__ d, long n4)
{
    long idx = (long)blockIdx.x * 256 + threadIdx.x;
    if (idx >= n4) return;
    float4 v = *(const float4*)&s[idx * 4];
    u32 w0 = (u32)f2b(v.x) | ((u32)f2b(v.y) << 16);
    u32 w1 = (u32)f2b(v.z) | ((u32)f2b(v.w) << 16);
    *(uint2*)&d[idx * 4] = make_uint2(w0, w1);
}

extern "C" void kernel_launch(void* const* d_in, const int* in_sizes, int n_in,
                              void* d_out, int out_size, void* d_ws, size_t ws_size,
                              hipStream_t stream)
{
    const long T = 3136;
    const float prm_scale = 0.07216878364870322f;  // 1/sqrt(192)

    const float* in1    = (const float*)d_in[0];
    const float* in2    = (const float*)d_in[1];
    const float* W1     = (const float*)d_in[2];
    const float* b1     = (const float*)d_in[3];
    const float* W2     = (const float*)d_in[4];
    const float* b2     = (const float*)d_in[5];
    const float* kqv_w  = (const float*)d_in[6];
    const float* kqv_b  = (const float*)d_in[7];
    const float* proj_w = (const float*)d_in[8];
    const float* proj_b = (const float*)d_in[9];
    const float* ln1_g  = (const float*)d_in[10];
    const float* ln1_b  = (const float*)d_in[11];
    const float* ln2_g  = (const float*)d_in[12];
    const float* ln2_b  = (const float*)d_in[13];
    const float* mlp_w1 = (const float*)d_in[14];
    const float* mlp_b1 = (const float*)d_in[15];
    const float* mlp_w2 = (const float*)d_in[16];
    const float* mlp_b2 = (const float*)d_in[17];
    const float* w_prm  = (const float*)d_in[18];
    float* out = (float*)d_out;

    char* p = (char*)d_ws;
    auto alloc = [&](long bytes)->char*{ char* r = p; p += (bytes + 255) & ~255L; return r; };

    // chunk-invariant bf16 weights
    u16* w1t   = (u16*)alloc(294912L * 2);
    u16* w2t   = (u16*)alloc(147456L * 2);
    u16* kqvt  = (u16*)alloc(442368L * 2);
    u16* prjt  = (u16*)alloc(147456L * 2);
    u16* m1t   = (u16*)alloc(147456L * 2);
    u16* m2t   = (u16*)alloc(147456L * 2);
    u16* wprmb = (u16*)alloc(256L * 384 * 2);
    char* chunkBase = p;

    // per-batch ws bytes (with big = a0/kqvb/mlp-hidden aliased):
    // bf16 rows: big 1152 + h1b 384 + xb 384 + xnb 384 + qpb 192 + vT 384 + kpT 256
    //          = 3136 * 2B = 6272 B/row; + Dn f32 + kpsum + kptvA + kptvb
    const long perBatch = 3136L * T * 2 + T * 4
                        + 192L * 4 + 7L * 73728 * 4 + 73728L * 2;
    const long fixed = (long)(chunkBase - (char*)d_ws) + (1L << 20);
    int nb = 2;
    for (int cand = 16; cand >= 2; cand >>= 1){
        if (fixed + (long)cand * perBatch + 128L * 1024 <= (long)ws_size){ nb = cand; break; }
    }

    const dim3 blk(256);

    wt_kernel<<<dim3((294912 + 255) / 256), blk, 0, stream>>>(W1, w1t, 768, 384, 294912);
    wt_kernel<<<dim3((147456 + 255) / 256), blk, 0, stream>>>(W2, w2t, 384, 384, 147456);
    wt_kernel<<<dim3((442368 + 255) / 256), blk, 0, stream>>>(kqv_w, kqvt, 384, 1152, 442368);
    wt_kernel<<<dim3((147456 + 255) / 256), blk, 0, stream>>>(proj_w, prjt, 384, 384, 147456);
    wt_kernel<<<dim3((147456 + 255) / 256), blk, 0, stream>>>(mlp_w1, m1t, 384, 384, 147456);
    wt_kernel<<<dim3((147456 + 255) / 256), blk, 0, stream>>>(mlp_w2, m2t, 384, 384, 147456);
    zero_kernel<<<dim3(64), blk, 0, stream>>>((float*)wprmb, 256L * 384 / 2);
    cvt_kernel<<<dim3((18432 + 255) / 256), blk, 0, stream>>>(w_prm, wprmb, 18432);

    for (int b0 = 0; b0 < 16; b0 += nb){
        const long Mc = (long)nb * T;
        const int  gy128 = (int)(Mc / 128);
        const float* i1 = in1 + (long)b0 * T * 384;
        const float* i2 = in2 + (long)b0 * T * 384;
        float* outc = out + (long)b0 * T * 384;

        p = chunkBase;
        u16*  big   = (u16*)alloc(Mc * 1152 * 2);   // a0 -> kqvb -> mlp hidden h
        u16*  h1b   = (u16*)alloc(Mc * 384 * 2);    // t_att
        u16*  xb    = (u16*)alloc(Mc * 384 * 2);    // x scratch (fusedA)
        u16*  xnb   = (u16*)alloc(Mc * 384 * 2);    // xn ; later z
        u16*  qpb   = (u16*)alloc(Mc * 192 * 2);    // qp (followed by allocs: OOB pad)
        u16*  vT    = (u16*)alloc(384L * Mc * 2);   // v^T
        u16*  kpT   = (u16*)alloc(256L * Mc * 2);   // kp^T (padded rows)
        float* Dn   = (float*)alloc(Mc * 4);
        float* kpsum= (float*)alloc((long)nb * 192 * 4);
        float* kptvA= (float*)alloc((long)nb * 7 * 73728 * 4);
        u16*  kptvb = (u16*)alloc((long)nb * 73728 * 2);
        (void)alloc(128L * 1024);

        u16* a0   = big;            // [Mc][768]
        u16* kqvb = big;            // [Mc][1152], written after a0 consumed
        u16* hbuf = big;            // [Mc][384], written after kqvb consumed

        // 0) a0 = bf16(concat)
        {
            long nq = Mc * 192;
            ca_kernel<<<dim3((unsigned)((nq + 255) / 256)), blk, 0, stream>>>(i1, i2, a0, nq);
        }
        // 1-3) fusedA: h1(LDS)=GELU(a0@W1t+b1); x=h1@W2t+b2 -> xb; xn=LN1(x) -> xnb
        fusedA<<<dim3(gy128), blk, 0, stream>>>(
            a0, w1t, b1, w2t, b2, ln1_g, ln1_b, xb, xnb);
        // 4) kqv = xn @ kqvt^T + kqv_b  [N=1152 fused] (overwrites big)
        gemm_bf16<0,0,0><<<dim3(9, gy128, 1), blk, 0, stream>>>(
            xnb, 384, kqvt, 384, kqvb, 1152, kqv_b, nullptr, nullptr, 0,
            (int)Mc, 1152, 384, 1, 0,0,0,0, 0.f);
        // 5) FAVOR dual: z=0 kpT (transposed), z=1 qp (row); xd in-GEMM
        gemm_bf16<10,0,1><<<dim3(2, gy128, 2), blk, 0, stream>>>(
            kqvb, 1152, wprmb, 384, kpT, (int)Mc, nullptr, nullptr, qpb, 192,
            (int)Mc, 192, 384, 1, 384, 0, 0, 0, prm_scale);
        // 6) kpsum from kpT rows
        kpsum2_kernel<<<dim3(nb * 48), blk, 0, stream>>>(kpT, kpsum, Mc, (int)T);
        // 7) vT = transpose of v
        trb_kernel<<<dim3(6, (unsigned)(Mc / 64)), blk, 0, stream>>>(kqvb + 768, 1152, vT, Mc);
        // 8) kptv: [384][192] = vT(b) @ kpT(b)^T, split-K=7 ; reduce
        gemm_bf16<8,0,1><<<dim3(2, 3, nb * 7), blk, 0, stream>>>(
            vT, (int)Mc, kpT, (int)Mc, kptvA, 192, nullptr, nullptr, nullptr, 0,
            384, 192, 3136, 7, 3136, 3136, 73728, 0, 0.f);
        kred_kernel<<<dim3((unsigned)((long)nb * 73728 / 256)), blk, 0, stream>>>(
            kptvA, kptvb, (long)nb * 73728);
        // 9) Dn
        dn_kernel<<<dim3((unsigned)(Mc / 4)), blk, 0, stream>>>(qpb, kpsum, Dn, (int)T);
        // 10) t_att = (qp @ kptv^T) / (Dn+1e-8)
        gemm_bf16<3,1,0><<<dim3(3, 25, nb), blk, 0, stream>>>(
            qpb, 192, kptvb, 192, h1b, 384, nullptr, Dn, nullptr, 0,
            (int)T, 384, 192, 1, T*192, 73728, T*384, T, 0.f);
        // 11) y = t_att @ proj + proj_b + v(bf16) -> outc f32
        gemm_bf16<9,0,0><<<dim3(3, gy128, 1), blk, 0, stream>>>(
            h1b, 384, prjt, 384, outc, 384, proj_b, nullptr, kqvb + 768, 1152,
            (int)Mc, 384, 384, 1, 0,0,0,0, 0.f);
        // 12) LN2 (f32 in) -> z bf16
        ln_kernel<1><<<dim3((unsigned)(Mc / 4)), blk, 0, stream>>>(outc, xnb, ln2_g, ln2_b);
        // 13) h = GELU(z @ mlp1 + b) -> hbuf (big, kqvb dead after step 11)
        gemm_bf16<1,0,0><<<dim3(3, gy128, 1), blk, 0, stream>>>(
            xnb, 384, m1t, 384, hbuf, 384, mlp_b1, nullptr, nullptr, 0,
            (int)Mc, 384, 384, 1, 0,0,0,0, 0.f);
        // 14) out = h @ mlp2 + b + y  (in-place residual)
        gemm_bf16<4,0,0><<<dim3(3, gy128, 1), blk, 0, stream>>>(
            hbuf, 384, m2t, 384, outc, 384, mlp_b2, nullptr, outc, 384,
            (int)Mc, 384, 384, 1, 0,0,0,0, 0.f);
    }
}

// Round 14
// 700.160 us; speedup vs baseline: 1.2321x; 1.2321x over previous
//
#include <hip/hip_runtime.h>
#include <math.h>

typedef unsigned short u16;
typedef unsigned int   u32;
typedef __attribute__((ext_vector_type(8))) short short8;
typedef __attribute__((ext_vector_type(4))) float f32x4;

typedef const void __attribute__((address_space(1))) gvoid_t;
typedef void       __attribute__((address_space(3))) svoid_t;

__device__ __forceinline__ void gload_lds16(const void* g, void* l){
    __builtin_amdgcn_global_load_lds((gvoid_t*)g, (svoid_t*)l, 16, 0, 0);
}

__device__ __forceinline__ float gelu_f(float x){
    return 0.5f * x * (1.0f + erff(x * 0.70710678118654752f));
}
__device__ __forceinline__ u16 f2b(float x){
    union{float f; u32 u;} v; v.f = x;
    u32 r = (v.u + 0x7fffu + ((v.u >> 16) & 1u)) >> 16;
    return (u16)r;
}
__device__ __forceinline__ float b2f(u16 h){
    union{u32 u; float f;} v; v.u = ((u32)h) << 16; return v.f;
}

// ===================== bf16 MFMA GEMM (frozen core) =====================
// EPI: 0:+bias->bf16  1:+bias,GELU->bf16  3:/(rowv[r]+1e-8)->bf16
//      4:+bias+resid(f32,ldr)->f32  8:plain bf16 store into per-splitK slice (bz*sC)
//      9:+bias+resid(bf16,ldr)->f32
//      10:FAVOR dual (in-GEMM xd): z0 transposed kpT store; z1 row store qp->resid
template<int EPI, int GUARD, int CGUARD>
__global__ __launch_bounds__(256)
void gemm_bf16(const u16* __restrict__ A, int lda,
               const u16* __restrict__ B, int ldb,
               void* __restrict__ Cv, int ldc,
               const float* __restrict__ bias,
               const float* __restrict__ rowv,
               void* __restrict__ resid, int ldr,
               int Mrows, int Ncols, int K, int splitK,
               long sA, long sB, long sC, long sRV,
               float scale)
{
    const int bz = blockIdx.z;
    const int b  = bz / splitK, kc = bz % splitK;
    A += (long)b * sA;  B += (long)b * sB;
    const float* rv = (EPI == 3) ? rowv + (long)b * sRV : nullptr;

    __shared__ u16 SMEM[32768];
    __shared__ float xds[128];
    u16* const As0 = SMEM;
    u16* const Bs0 = SMEM + 8192;
    u16* const As1 = SMEM + 16384;
    u16* const Bs1 = SMEM + 24576;

    const int tid = threadIdx.x;

    const int gx  = gridDim.x;
    const int nwg = gx * gridDim.y;
    const int L   = blockIdx.y * gx + blockIdx.x;
    const int q8  = nwg >> 3, r8 = nwg & 7;
    const int xc  = L & 7,   i8 = L >> 3;
    const int nid = (xc < r8 ? xc * (q8 + 1) : r8 * (q8 + 1) + (xc - r8) * q8) + i8;
    const int row0 = (nid / gx) * 128, col0 = (nid % gx) * 128;

    f32x4 acc[4][4] = {};
    float sqacc[4] = {0.f, 0.f, 0.f, 0.f};

    const int l  = tid & 63, w4 = tid >> 6;
    const int wr = w4 >> 1, wc = w4 & 1;
    const int g  = l >> 4,  mr = l & 15;

    const int kLen   = K / splitK;
    const int kStart = kc * kLen;
    const int nt     = kLen / 64;

    const int m0   = w4 * 8 + (l >> 3);
    const int k8s  = (l & 7) ^ (m0 & 7);
    const int lBase = w4 * 512 + l * 8;
    const u16* gA0 = A + (long)(row0 + m0) * lda + kStart + k8s * 8;
    const u16* gB0 = B + (long)(col0 + m0) * ldb + kStart + k8s * 8;

    int aOff[4], bOff[4], sl[2];
    #pragma unroll
    for (int i = 0; i < 4; i++){
        aOff[i] = (wr * 64 + i * 16 + mr) * 64;
        bOff[i] = (wc * 64 + i * 16 + mr) * 64;
    }
    #pragma unroll
    for (int kk = 0; kk < 2; kk++)
        sl[kk] = (((kk * 4 + g) ^ (mr & 7)) & 7) * 8;

#define STAGE(AS, BS, KOFF)                                             \
    {                                                                   \
        _Pragma("unroll")                                               \
        for (int q = 0; q < 4; q++){                                    \
            gload_lds16(gA0 + (long)q * 32 * lda + (KOFF), &(AS)[lBase + q * 2048]); \
            gload_lds16(gB0 + (long)q * 32 * ldb + (KOFF), &(BS)[lBase + q * 2048]); \
        }                                                               \
    }

#define COMPUTE(AS, BS)                                                 \
    {                                                                   \
        short8 af[2][4], bfr[2][4];                                     \
        _Pragma("unroll")                                               \
        for (int kk = 0; kk < 2; kk++){                                 \
            _Pragma("unroll")                                           \
            for (int i = 0; i < 4; i++){                                \
                af[kk][i]  = *(const short8*)&(AS)[aOff[i] + sl[kk]];   \
                bfr[kk][i] = *(const short8*)&(BS)[bOff[i] + sl[kk]];   \
            }                                                           \
        }                                                               \
        if (EPI == 10){                                                 \
            _Pragma("unroll")                                           \
            for (int kk = 0; kk < 2; kk++)                              \
                _Pragma("unroll")                                       \
                for (int i = 0; i < 4; i++)                             \
                    _Pragma("unroll")                                   \
                    for (int e = 0; e < 8; e++){                        \
                        float f_ = b2f((u16)af[kk][i][e]);              \
                        sqacc[i] += f_ * f_;                            \
                    }                                                   \
        }                                                               \
        _Pragma("unroll")                                               \
        for (int kk = 0; kk < 2; kk++)                                  \
            _Pragma("unroll")                                           \
            for (int i = 0; i < 4; i++)                                 \
                _Pragma("unroll")                                       \
                for (int j = 0; j < 4; j++)                             \
                    acc[i][j] = __builtin_amdgcn_mfma_f32_16x16x32_bf16(af[kk][i], bfr[kk][j], acc[i][j], 0, 0, 0); \
    }

    STAGE(As0, Bs0, 0);

    for (int t = 0; t < nt; ){
        __syncthreads();
        if (t + 1 < nt) STAGE(As1, Bs1, (t + 1) * 64);
        COMPUTE(As0, Bs0);
        t++;
        if (t >= nt) break;
        __syncthreads();
        if (t + 1 < nt) STAGE(As0, Bs0, (t + 1) * 64);
        COMPUTE(As1, Bs1);
        t++;
    }
#undef STAGE
#undef COMPUTE

    if (EPI == 10){
        #pragma unroll
        for (int i = 0; i < 4; i++){
            float s = sqacc[i];
            s += __shfl_xor(s, 16);
            s += __shfl_xor(s, 32);
            if (l < 16) xds[wr * 64 + i * 16 + l] = 0.5f * s;
        }
    }
    __syncthreads();

    float* Cf = (float*)Cv + (long)b * sC;
    u16*   Cb = (u16*)Cv   + (EPI == 10 ? 0L : (EPI == 8 ? (long)bz : (long)b) * sC);

    if (EPI == 10 && bz == 0){
        #pragma unroll
        for (int i = 0; i < 4; i++){
            #pragma unroll
            for (int j = 0; j < 4; j++){
                const int col = col0 + wc * 64 + j * 16 + mr;
                if (CGUARD && col >= Ncols) continue;
                const int lrow = wr * 64 + i * 16 + g * 4;
                u16 pk[4];
                #pragma unroll
                for (int r = 0; r < 4; r++)
                    pk[r] = f2b(expf(acc[i][j][r] - xds[lrow + r]) * scale);
                *(ushort4*)&Cb[(long)col * ldc + row0 + lrow] = *(ushort4*)pk;
            }
        }
        return;
    }

    constexpr bool OUTF32 = (EPI == 4 || EPI == 9);
    float* const Sf = (float*)SMEM;
    #pragma unroll
    for (int i = 0; i < 4; i++){
        #pragma unroll
        for (int j = 0; j < 4; j++){
            const int cl = wc * 64 + j * 16 + mr;
            const float bv = (EPI == 0 || EPI == 1 || EPI == 4 || EPI == 9)
                           ? bias[col0 + cl] : 0.f;
            #pragma unroll
            for (int r = 0; r < 4; r++){
                const int rl = wr * 64 + i * 16 + g * 4 + r;
                float vv = acc[i][j][r];
                if      (EPI == 1)  vv = gelu_f(vv + bv);
                else if (EPI == 3)  vv = vv / (rv[row0 + rl] + 1e-8f);
                else if (EPI == 10) vv = expf(vv - xds[rl]) * scale;
                else                vv += bv;   // EPI 0,4,9 (+0 for 8)
                if (OUTF32) Sf[rl * 128 + cl] = vv;
                else        SMEM[rl * 128 + cl] = f2b(vv);
            }
        }
    }
    __syncthreads();

    if (OUTF32){
        #pragma unroll
        for (int s = 0; s < 16; s++){
            const int qi = s * 256 + tid;
            const int rl = qi >> 5, c4 = (qi & 31) << 2;
            const int row = row0 + rl, col = col0 + c4;
            if (GUARD && row >= Mrows) continue;
            if (CGUARD && col >= Ncols) continue;
            float4 v = *(float4*)&Sf[rl * 128 + c4];
            if (EPI == 4){
                float4 rr = *(const float4*)&((const float*)resid)[(long)row * ldr + col];
                v.x += rr.x; v.y += rr.y; v.z += rr.z; v.w += rr.w;
            } else if (EPI == 9){
                ushort4 rh = *(const ushort4*)&((const u16*)resid)[(long)row * ldr + col];
                v.x += b2f(rh.x); v.y += b2f(rh.y); v.z += b2f(rh.z); v.w += b2f(rh.w);
            }
            *(float4*)&Cf[(long)row * ldc + col] = v;
        }
    } else {
        u16* dst; long ld;
        if (EPI == 10){ dst = (u16*)resid; ld = ldr; }
        else          { dst = Cb;          ld = ldc; }
        #pragma unroll
        for (int s = 0; s < 8; s++){
            const int oi = s * 256 + tid;
            const int rl = oi >> 4, c8 = (oi & 15) << 3;
            const int row = row0 + rl, col = col0 + c8;
            if (GUARD && row >= Mrows) continue;
            if (CGUARD && col >= Ncols) continue;
            *(uint4*)&dst[(long)row * ld + col] = *(uint4*)&SMEM[rl * 128 + c8];
        }
    }
}

// bf16 strided transpose: out[(cb+c)*R + rb+r] = in[(rb+r)*inStride + cb+c]
__global__ __launch_bounds__(256)
void trb_kernel(const u16* __restrict__ in, long inStride, u16* __restrict__ out, long R)
{
    __shared__ u16 t[64][72];
    const long cb = (long)blockIdx.x * 64, rb = (long)blockIdx.y * 64;
    const int tl = threadIdx.x & 63, tw = threadIdx.x >> 6;
    #pragma unroll
    for (int i = 0; i < 16; i++){
        const int r = tw + i * 4;
        t[r][tl] = in[(rb + r) * inStride + cb + tl];
    }
    __syncthreads();
    #pragma unroll
    for (int i = 0; i < 16; i++){
        const int c = tw + i * 4;
        out[(cb + c) * R + rb + tl] = t[tl][c];
    }
}

// kptvb[b][i] = bf16( sum_{kc<7} slices_bf16[b*7+kc][i] )
__global__ __launch_bounds__(256)
void kred_kernel(const u16* __restrict__ in, u16* __restrict__ out, long n)
{
    long idx = (long)blockIdx.x * 256 + threadIdx.x;
    if (idx >= n) return;
    const long b = idx / 73728, r = idx - b * 73728;
    const u16* s = in + b * 7 * 73728L + r;
    float acc = 0.f;
    #pragma unroll
    for (int kc = 0; kc < 7; kc++) acc += b2f(s[kc * 73728L]);
    out[idx] = f2b(acc);
}

// LayerNorm over D=384; input f32 (INF32=1) or bf16 (INF32=0); bf16 out (may alias in).
template<int INF32>
__global__ __launch_bounds__(256)
void ln_kernel(const void* __restrict__ xv, u16* __restrict__ ob,
               const float* __restrict__ g, const float* __restrict__ bta)
{
    const int lane = threadIdx.x & 63;
    const long r = (long)blockIdx.x * 4 + (threadIdx.x >> 6);
    float v[6]; float s = 0.f;
    #pragma unroll
    for (int i = 0; i < 6; i++){
        const int c = lane + i * 64;
        v[i] = INF32 ? ((const float*)xv)[r * 384 + c]
                     : b2f(((const u16*)xv)[r * 384 + c]);
        s += v[i];
    }
    #pragma unroll
    for (int off = 32; off; off >>= 1) s += __shfl_xor(s, off);
    const float mu = s * (1.0f/384.0f);
    float q = 0.f;
    #pragma unroll
    for (int i = 0; i < 6; i++){ float d = v[i] - mu; q += d*d; }
    #pragma unroll
    for (int off = 32; off; off >>= 1) q += __shfl_xor(q, off);
    const float inv = rsqrtf(q * (1.0f/384.0f) + 1e-5f);
    #pragma unroll
    for (int i = 0; i < 6; i++){
        const int c = lane + i*64;
        ob[r * 384 + c] = f2b((v[i] - mu) * inv * g[c] + bta[c]);
    }
}

// Dn[r] = dot(qp_bf16[r,:192], kpsum[r/T,:192])
__global__ __launch_bounds__(256)
void dn_kernel(const u16* __restrict__ qp, const float* __restrict__ kpsum,
               float* __restrict__ Dn, int T)
{
    const int lane = threadIdx.x & 63;
    const long r = (long)blockIdx.x * 4 + (threadIdx.x >> 6);
    const int b = (int)(r / T);
    const u16* qr = qp + r * 192;
    const float* ks = kpsum + (long)b * 192;
    float s = 0.f;
    #pragma unroll
    for (int i = 0; i < 3; i++){ const int m = lane + i*64; s += b2f(qr[m]) * ks[m]; }
    #pragma unroll
    for (int off = 32; off; off >>= 1) s += __shfl_xor(s, off);
    if (lane == 0) Dn[r] = s;
}

// kpsum[bl][m] = sum_t kpT[m][bl*T + t]
__global__ __launch_bounds__(256)
void kpsum2_kernel(const u16* __restrict__ kpT, float* __restrict__ kpsum, long Mc, int T)
{
    const int lane = threadIdx.x & 63;
    const int gw = blockIdx.x * 4 + (threadIdx.x >> 6);
    const int m = gw % 192, bl = gw / 192;
    const u16* row = kpT + (long)m * Mc + (long)bl * T;
    float s = 0.f;
    for (int i = lane; i < T; i += 64) s += b2f(row[i]);
    #pragma unroll
    for (int off = 32; off; off >>= 1) s += __shfl_xor(s, off);
    if (lane == 0) kpsum[bl * 192 + m] = s;
}

__global__ __launch_bounds__(256)
void zero_kernel(float* __restrict__ p, long n)
{
    long i = (long)blockIdx.x * 256 + threadIdx.x;
    long stride = (long)gridDim.x * 256;
    for (; i < n; i += stride) p[i] = 0.f;
}

// concat(in1,in2) row-major -> bf16 [Mc][768]
__global__ __launch_bounds__(256)
void ca_kernel(const float* __restrict__ i1, const float* __restrict__ i2,
               u16* __restrict__ a0, long nquad)
{
    long idx = (long)blockIdx.x * 256 + threadIdx.x;
    if (idx >= nquad) return;
    const long r = idx / 192;
    const int  c0 = (int)(idx % 192) * 4;
    const float* src = (c0 < 384) ? &i1[r * 384 + c0] : &i2[r * 384 + (c0 - 384)];
    float4 v = *(const float4*)src;
    u32 w0 = (u32)f2b(v.x) | ((u32)f2b(v.y) << 16);
    u32 w1 = (u32)f2b(v.z) | ((u32)f2b(v.w) << 16);
    *(uint2*)&a0[r * 768 + c0] = make_uint2(w0, w1);
}

// wt[n*K + k] = bf16(w[k*N + n])
__global__ __launch_bounds__(256)
void wt_kernel(const float* __restrict__ w, u16* __restrict__ wt, int K, int N, long total)
{
    long idx = (long)blockIdx.x * 256 + threadIdx.x;
    if (idx >= total) return;
    const long n = idx / K, k = idx - n * K;
    wt[idx] = f2b(w[k * N + n]);
}

// flat f32 -> bf16
__global__ __launch_bounds__(256)
void cvt_kernel(const float* __restrict__ s, u16* __restrict__ d, long n4)
{
    long idx = (long)blockIdx.x * 256 + threadIdx.x;
    if (idx >= n4) return;
    float4 v = *(const float4*)&s[idx * 4];
    u32 w0 = (u32)f2b(v.x) | ((u32)f2b(v.y) << 16);
    u32 w1 = (u32)f2b(v.z) | ((u32)f2b(v.w) << 16);
    *(uint2*)&d[idx * 4] = make_uint2(w0, w1);
}

extern "C" void kernel_launch(void* const* d_in, const int* in_sizes, int n_in,
                              void* d_out, int out_size, void* d_ws, size_t ws_size,
                              hipStream_t stream)
{
    const long T = 3136;
    const float prm_scale = 0.07216878364870322f;  // 1/sqrt(192)

    const float* in1    = (const float*)d_in[0];
    const float* in2    = (const float*)d_in[1];
    const float* W1     = (const float*)d_in[2];
    const float* b1     = (const float*)d_in[3];
    const float* W2     = (const float*)d_in[4];
    const float* b2     = (const float*)d_in[5];
    const float* kqv_w  = (const float*)d_in[6];
    const float* kqv_b  = (const float*)d_in[7];
    const float* proj_w = (const float*)d_in[8];
    const float* proj_b = (const float*)d_in[9];
    const float* ln1_g  = (const float*)d_in[10];
    const float* ln1_b  = (const float*)d_in[11];
    const float* ln2_g  = (const float*)d_in[12];
    const float* ln2_b  = (const float*)d_in[13];
    const float* mlp_w1 = (const float*)d_in[14];
    const float* mlp_b1 = (const float*)d_in[15];
    const float* mlp_w2 = (const float*)d_in[16];
    const float* mlp_b2 = (const float*)d_in[17];
    const float* w_prm  = (const float*)d_in[18];
    float* out = (float*)d_out;

    char* p = (char*)d_ws;
    auto alloc = [&](long bytes)->char*{ char* r = p; p += (bytes + 255) & ~255L; return r; };

    // chunk-invariant bf16 weights
    u16* w1t   = (u16*)alloc(294912L * 2);
    u16* w2t   = (u16*)alloc(147456L * 2);
    u16* kqvt  = (u16*)alloc(442368L * 2);
    u16* prjt  = (u16*)alloc(147456L * 2);
    u16* m1t   = (u16*)alloc(147456L * 2);
    u16* m2t   = (u16*)alloc(147456L * 2);
    u16* wprmb = (u16*)alloc(256L * 384 * 2);
    char* chunkBase = p;

    // per-batch ws bytes (slimmed):
    // bf16 cols: big 1152 + xb 384 + qpb 192 + vT 384 + kpT 256 = 2368 * T * 2
    // + Dn T*4 + kpsum 192*4 + kptvA(bf16) 7*73728*2 + kptvb 73728*2
    const long perBatch = 2368L * T * 2 + T * 4
                        + 192L * 4 + 7L * 73728 * 2 + 73728L * 2;
    const long fixed = (long)(chunkBase - (char*)d_ws) + (1L << 20);
    int nb = 2;
    for (int cand = 16; cand >= 2; cand >>= 1){
        if (fixed + (long)cand * perBatch + 128L * 1024 <= (long)ws_size){ nb = cand; break; }
    }

    const dim3 blk(256);

    wt_kernel<<<dim3((294912 + 255) / 256), blk, 0, stream>>>(W1, w1t, 768, 384, 294912);
    wt_kernel<<<dim3((147456 + 255) / 256), blk, 0, stream>>>(W2, w2t, 384, 384, 147456);
    wt_kernel<<<dim3((442368 + 255) / 256), blk, 0, stream>>>(kqv_w, kqvt, 384, 1152, 442368);
    wt_kernel<<<dim3((147456 + 255) / 256), blk, 0, stream>>>(proj_w, prjt, 384, 384, 147456);
    wt_kernel<<<dim3((147456 + 255) / 256), blk, 0, stream>>>(mlp_w1, m1t, 384, 384, 147456);
    wt_kernel<<<dim3((147456 + 255) / 256), blk, 0, stream>>>(mlp_w2, m2t, 384, 384, 147456);
    zero_kernel<<<dim3(64), blk, 0, stream>>>((float*)wprmb, 256L * 384 / 2);
    cvt_kernel<<<dim3((18432 + 255) / 256), blk, 0, stream>>>(w_prm, wprmb, 18432);

    for (int b0 = 0; b0 < 16; b0 += nb){
        const long Mc = (long)nb * T;
        const int  gy128 = (int)(Mc / 128);
        const float* i1 = in1 + (long)b0 * T * 384;
        const float* i2 = in2 + (long)b0 * T * 384;
        float* outc = out + (long)b0 * T * 384;

        p = chunkBase;
        u16*  big   = (u16*)alloc(Mc * 1152 * 2);   // a0(768)+h1(tail) -> kqvb -> mlp hidden
        u16*  xb    = (u16*)alloc(Mc * 384 * 2);    // x -> xn -> t_att -> z
        u16*  qpb   = (u16*)alloc(Mc * 192 * 2);    // qp (followed by allocs: OOB pad)
        u16*  vT    = (u16*)alloc(384L * Mc * 2);   // v^T
        u16*  kpT   = (u16*)alloc(256L * Mc * 2);   // kp^T (padded rows)
        float* Dn   = (float*)alloc(Mc * 4);
        float* kpsum= (float*)alloc((long)nb * 192 * 4);
        u16*  kptvA = (u16*)alloc((long)nb * 7 * 73728 * 2);   // bf16 split-K slices
        u16*  kptvb = (u16*)alloc((long)nb * 73728 * 2);
        (void)alloc(128L * 1024);

        u16* a0   = big;                      // [Mc][768]
        u16* h1   = big + Mc * 768;           // [Mc][384] (tail of big)
        u16* kqvb = big;                      // [Mc][1152] after a0/h1 dead
        u16* hbuf = big;                      // [Mc][384] after kqvb dead

        // 0) a0 = bf16(concat)
        {
            long nq = Mc * 192;
            ca_kernel<<<dim3((unsigned)((nq + 255) / 256)), blk, 0, stream>>>(i1, i2, a0, nq);
        }
        // 1) h1 = GELU(a0 @ W1t^T + b1) -> big tail
        gemm_bf16<1,0,0><<<dim3(3, gy128, 1), blk, 0, stream>>>(
            a0, 768, w1t, 768, h1, 384, b1, nullptr, nullptr, 0,
            (int)Mc, 384, 768, 1, 0,0,0,0, 0.f);
        // 2) x = h1 @ W2t^T + b2 -> xb [bf16]
        gemm_bf16<0,0,0><<<dim3(3, gy128, 1), blk, 0, stream>>>(
            h1, 384, w2t, 384, xb, 384, b2, nullptr, nullptr, 0,
            (int)Mc, 384, 384, 1, 0,0,0,0, 0.f);
        // 3) LN1 in-place: xn -> xb
        ln_kernel<0><<<dim3((unsigned)(Mc / 4)), blk, 0, stream>>>(xb, xb, ln1_g, ln1_b);
        // 4) kqv = xn @ kqvt^T + kqv_b -> big [N=1152]
        gemm_bf16<0,0,0><<<dim3(9, gy128, 1), blk, 0, stream>>>(
            xb, 384, kqvt, 384, kqvb, 1152, kqv_b, nullptr, nullptr, 0,
            (int)Mc, 1152, 384, 1, 0,0,0,0, 0.f);
        // 5) FAVOR dual: z=0 kpT (transposed), z=1 qp (row); xd in-GEMM
        gemm_bf16<10,0,1><<<dim3(2, gy128, 2), blk, 0, stream>>>(
            kqvb, 1152, wprmb, 384, kpT, (int)Mc, nullptr, nullptr, qpb, 192,
            (int)Mc, 192, 384, 1, 384, 0, 0, 0, prm_scale);
        // 6) kpsum from kpT rows
        kpsum2_kernel<<<dim3(nb * 48), blk, 0, stream>>>(kpT, kpsum, Mc, (int)T);
        // 7) vT = transpose of v
        trb_kernel<<<dim3(6, (unsigned)(Mc / 64)), blk, 0, stream>>>(kqvb + 768, 1152, vT, Mc);
        // 8) kptv: [384][192] = vT(b) @ kpT(b)^T, split-K=7 bf16 slices ; reduce
        gemm_bf16<8,0,1><<<dim3(2, 3, nb * 7), blk, 0, stream>>>(
            vT, (int)Mc, kpT, (int)Mc, kptvA, 192, nullptr, nullptr, nullptr, 0,
            384, 192, 3136, 7, 3136, 3136, 73728, 0, 0.f);
        kred_kernel<<<dim3((unsigned)((long)nb * 73728 / 256)), blk, 0, stream>>>(
            kptvA, kptvb, (long)nb * 73728);
        // 9) Dn
        dn_kernel<<<dim3((unsigned)(Mc / 4)), blk, 0, stream>>>(qpb, kpsum, Dn, (int)T);
        // 10) t_att = (qp @ kptv^T)/(Dn+1e-8) -> xb (xn dead after step 4)
        gemm_bf16<3,1,0><<<dim3(3, 25, nb), blk, 0, stream>>>(
            qpb, 192, kptvb, 192, xb, 384, nullptr, Dn, nullptr, 0,
            (int)T, 384, 192, 1, T*192, 73728, T*384, T, 0.f);
        // 11) y = t_att @ proj + proj_b + v(bf16) -> outc f32
        gemm_bf16<9,0,0><<<dim3(3, gy128, 1), blk, 0, stream>>>(
            xb, 384, prjt, 384, outc, 384, proj_b, nullptr, kqvb + 768, 1152,
            (int)Mc, 384, 384, 1, 0,0,0,0, 0.f);
        // 12) LN2: z -> xb (t_att dead after step 11)
        ln_kernel<1><<<dim3((unsigned)(Mc / 4)), blk, 0, stream>>>(outc, xb, ln2_g, ln2_b);
        // 13) h = GELU(z @ mlp1 + b) -> hbuf (big; kqv dead after step 11)
        gemm_bf16<1,0,0><<<dim3(3, gy128, 1), blk, 0, stream>>>(
            xb, 384, m1t, 384, hbuf, 384, mlp_b1, nullptr, nullptr, 0,
            (int)Mc, 384, 384, 1, 0,0,0,0, 0.f);
        // 14) out = h @ mlp2 + b + y  (in-place residual)
        gemm_bf16<4,0,0><<<dim3(3, gy128, 1), blk, 0, stream>>>(
            hbuf, 384, m2t, 384, outc, 384, mlp_b2, nullptr, outc, 384,
            (int)Mc, 384, 384, 1, 0,0,0,0, 0.f);
    }
}

// Round 15
// 534.502 us; speedup vs baseline: 1.6139x; 1.3099x over previous
//
#include <hip/hip_runtime.h>
#include <math.h>

typedef unsigned short u16;
typedef unsigned int   u32;
typedef __attribute__((ext_vector_type(8))) short short8;
typedef __attribute__((ext_vector_type(4))) float f32x4;

typedef const void __attribute__((address_space(1))) gvoid_t;
typedef void       __attribute__((address_space(3))) svoid_t;

__device__ __forceinline__ void gload_lds16(const void* g, void* l){
    __builtin_amdgcn_global_load_lds((gvoid_t*)g, (svoid_t*)l, 16, 0, 0);
}

__device__ __forceinline__ float gelu_f(float x){
    return 0.5f * x * (1.0f + erff(x * 0.70710678118654752f));
}
__device__ __forceinline__ u16 f2b(float x){
    union{float f; u32 u;} v; v.f = x;
    u32 r = (v.u + 0x7fffu + ((v.u >> 16) & 1u)) >> 16;
    return (u16)r;
}
__device__ __forceinline__ float b2f(u16 h){
    union{u32 u; float f;} v; v.u = ((u32)h) << 16; return v.f;
}

// ===================== bf16 MFMA GEMM (32KB LDS, single-buffer staging) ===============
// Tile 128x128, BK=64, 4 waves, XOR-swizzled LDS, global_load_lds staging,
// T1 XCD-chunked block swizzle. Single-buffered K-loop (dbuf measured ~0 gain;
// 32KB LDS -> 3 blocks/CU instead of 2).
// EPI: 0:+bias->bf16  1:+bias,GELU->bf16  3:/(rowv[r]+1e-8)->bf16
//      8:plain bf16 store into per-splitK slice (bz*sC)
//      9:+bias+resid(bf16,ldr)->f32 DIRECT scatter
//      10:FAVOR dual (in-GEMM xd): z0 transposed kpT store; z1 qp row store->resid
//      11:+bias+resid(bf16,ldr)->bf16 (resid added coalesced in store phase)
template<int EPI, int GUARD, int CGUARD>
__global__ __launch_bounds__(256)
void gemm_bf16(const u16* __restrict__ A, int lda,
               const u16* __restrict__ B, int ldb,
               void* __restrict__ Cv, int ldc,
               const float* __restrict__ bias,
               const float* __restrict__ rowv,
               void* __restrict__ resid, int ldr,
               int Mrows, int Ncols, int K, int splitK,
               long sA, long sB, long sC, long sRV,
               float scale)
{
    const int bz = blockIdx.z;
    const int b  = bz / splitK, kc = bz % splitK;
    A += (long)b * sA;  B += (long)b * sB;
    const float* rv = (EPI == 3) ? rowv + (long)b * sRV : nullptr;

    __shared__ u16 SMEM[16384];     // 32KB: A/B tiles during loop, bf16 C-tile in epilogue
    __shared__ float xds[128];
    u16* const As = SMEM;
    u16* const Bs = SMEM + 8192;

    const int tid = threadIdx.x;

    const int gx  = gridDim.x;
    const int nwg = gx * gridDim.y;
    const int L   = blockIdx.y * gx + blockIdx.x;
    const int q8  = nwg >> 3, r8 = nwg & 7;
    const int xc  = L & 7,   i8 = L >> 3;
    const int nid = (xc < r8 ? xc * (q8 + 1) : r8 * (q8 + 1) + (xc - r8) * q8) + i8;
    const int row0 = (nid / gx) * 128, col0 = (nid % gx) * 128;

    f32x4 acc[4][4] = {};
    float sqacc[4] = {0.f, 0.f, 0.f, 0.f};

    const int l  = tid & 63, w4 = tid >> 6;
    const int wr = w4 >> 1, wc = w4 & 1;
    const int g  = l >> 4,  mr = l & 15;

    const int kLen   = K / splitK;
    const int kStart = kc * kLen;
    const int nt     = kLen / 64;

    const int m0   = w4 * 8 + (l >> 3);
    const int k8s  = (l & 7) ^ (m0 & 7);
    const int lBase = w4 * 512 + l * 8;
    const u16* gA0 = A + (long)(row0 + m0) * lda + kStart + k8s * 8;
    const u16* gB0 = B + (long)(col0 + m0) * ldb + kStart + k8s * 8;

    int aOff[4], bOff[4], sl[2];
    #pragma unroll
    for (int i = 0; i < 4; i++){
        aOff[i] = (wr * 64 + i * 16 + mr) * 64;
        bOff[i] = (wc * 64 + i * 16 + mr) * 64;
    }
    #pragma unroll
    for (int kk = 0; kk < 2; kk++)
        sl[kk] = (((kk * 4 + g) ^ (mr & 7)) & 7) * 8;

    for (int t = 0; t < nt; t++){
        __syncthreads();            // protect prev COMPUTE's reads
        #pragma unroll
        for (int q = 0; q < 4; q++){
            gload_lds16(gA0 + (long)q * 32 * lda + t * 64, &As[lBase + q * 2048]);
            gload_lds16(gB0 + (long)q * 32 * ldb + t * 64, &Bs[lBase + q * 2048]);
        }
        __syncthreads();            // vmcnt drained -> tiles visible

        short8 af[2][4], bfr[2][4];
        #pragma unroll
        for (int kk = 0; kk < 2; kk++)
            #pragma unroll
            for (int i = 0; i < 4; i++){
                af[kk][i]  = *(const short8*)&As[aOff[i] + sl[kk]];
                bfr[kk][i] = *(const short8*)&Bs[bOff[i] + sl[kk]];
            }
        if (EPI == 10){
            #pragma unroll
            for (int kk = 0; kk < 2; kk++)
                #pragma unroll
                for (int i = 0; i < 4; i++)
                    #pragma unroll
                    for (int e = 0; e < 8; e++){
                        float f_ = b2f((u16)af[kk][i][e]);
                        sqacc[i] += f_ * f_;
                    }
        }
        #pragma unroll
        for (int kk = 0; kk < 2; kk++)
            #pragma unroll
            for (int i = 0; i < 4; i++)
                #pragma unroll
                for (int j = 0; j < 4; j++)
                    acc[i][j] = __builtin_amdgcn_mfma_f32_16x16x32_bf16(af[kk][i], bfr[kk][j], acc[i][j], 0, 0, 0);
    }

    if (EPI == 10){
        #pragma unroll
        for (int i = 0; i < 4; i++){
            float s = sqacc[i];
            s += __shfl_xor(s, 16);
            s += __shfl_xor(s, 32);
            if (l < 16) xds[wr * 64 + i * 16 + l] = 0.5f * s;
        }
    }
    __syncthreads();   // last COMPUTE reads done; xds visible; SMEM reusable

    float* Cf = (float*)Cv + (long)b * sC;
    u16*   Cb = (u16*)Cv   + (EPI == 10 ? 0L : (EPI == 8 ? (long)bz : (long)b) * sC);

    if (EPI == 10 && bz == 0){
        // custom transposed kpT store (8B-packed column writes)
        #pragma unroll
        for (int i = 0; i < 4; i++){
            #pragma unroll
            for (int j = 0; j < 4; j++){
                const int col = col0 + wc * 64 + j * 16 + mr;
                if (CGUARD && col >= Ncols) continue;
                const int lrow = wr * 64 + i * 16 + g * 4;
                u16 pk[4];
                #pragma unroll
                for (int r = 0; r < 4; r++)
                    pk[r] = f2b(expf(acc[i][j][r] - xds[lrow + r]) * scale);
                *(ushort4*)&Cb[(long)col * ldc + row0 + lrow] = *(ushort4*)pk;
            }
        }
        return;
    }

    if (EPI == 9){
        // f32 out, bf16 residual -- direct scatter
        #pragma unroll
        for (int i = 0; i < 4; i++){
            #pragma unroll
            for (int j = 0; j < 4; j++){
                const int col = col0 + wc * 64 + j * 16 + mr;
                if (CGUARD && col >= Ncols) continue;
                const float bv = bias[col];
                #pragma unroll
                for (int r = 0; r < 4; r++){
                    const int row = row0 + wr * 64 + i * 16 + g * 4 + r;
                    if (GUARD && row >= Mrows) continue;
                    const float vv = acc[i][j][r] + bv
                        + b2f(((const u16*)resid)[(long)row * ldr + col]);
                    Cf[(long)row * ldc + col] = vv;
                }
            }
        }
        return;
    }

    // ---- bf16 bounce epilogue (EPI 0,1,3,8,10z1,11) ----
    #pragma unroll
    for (int i = 0; i < 4; i++){
        #pragma unroll
        for (int j = 0; j < 4; j++){
            const int cl = wc * 64 + j * 16 + mr;
            const float bv = (EPI == 0 || EPI == 1 || EPI == 11)
                           ? bias[col0 + cl] : 0.f;
            #pragma unroll
            for (int r = 0; r < 4; r++){
                const int rl = wr * 64 + i * 16 + g * 4 + r;
                float vv = acc[i][j][r];
                if      (EPI == 1)  vv = gelu_f(vv + bv);
                else if (EPI == 3)  vv = vv / (rv[row0 + rl] + 1e-8f);
                else if (EPI == 10) vv = expf(vv - xds[rl]) * scale;
                else                vv += bv;   // EPI 0, 8(+0), 11
                SMEM[rl * 128 + cl] = f2b(vv);
            }
        }
    }
    __syncthreads();

    u16* dst; long ld;
    if (EPI == 10){ dst = (u16*)resid; ld = ldr; }
    else          { dst = Cb;          ld = ldc; }
    #pragma unroll
    for (int s = 0; s < 8; s++){
        const int oi = s * 256 + tid;
        const int rl = oi >> 4, c8 = (oi & 15) << 3;
        const int row = row0 + rl, col = col0 + c8;
        if (GUARD && row >= Mrows) continue;
        if (CGUARD && col >= Ncols) continue;
        uint4 pv = *(uint4*)&SMEM[rl * 128 + c8];
        if (EPI == 11){
            const u16* rp = (const u16*)resid + (long)row * ldr + col;
            uint4 rv4 = *(const uint4*)rp;
            u16* a = (u16*)&pv; const u16* c = (const u16*)&rv4;
            #pragma unroll
            for (int e = 0; e < 8; e++) a[e] = f2b(b2f(a[e]) + b2f(c[e]));
        }
        *(uint4*)&dst[(long)row * ld + col] = pv;
    }
}

// bf16 strided transpose: out[(cb+c)*R + rb+r] = in[(rb+r)*inStride + cb+c]
__global__ __launch_bounds__(256)
void trb_kernel(const u16* __restrict__ in, long inStride, u16* __restrict__ out, long R)
{
    __shared__ u16 t[64][72];
    const long cb = (long)blockIdx.x * 64, rb = (long)blockIdx.y * 64;
    const int tl = threadIdx.x & 63, tw = threadIdx.x >> 6;
    #pragma unroll
    for (int i = 0; i < 16; i++){
        const int r = tw + i * 4;
        t[r][tl] = in[(rb + r) * inStride + cb + tl];
    }
    __syncthreads();
    #pragma unroll
    for (int i = 0; i < 16; i++){
        const int c = tw + i * 4;
        out[(cb + c) * R + rb + tl] = t[tl][c];
    }
}

// kptvb[b][i] = bf16( sum_{kc<7} slices_bf16[b*7+kc][i] )
__global__ __launch_bounds__(256)
void kred_kernel(const u16* __restrict__ in, u16* __restrict__ out, long n)
{
    long idx = (long)blockIdx.x * 256 + threadIdx.x;
    if (idx >= n) return;
    const long b = idx / 73728, r = idx - b * 73728;
    const u16* s = in + b * 7 * 73728L + r;
    float acc = 0.f;
    #pragma unroll
    for (int kc = 0; kc < 7; kc++) acc += b2f(s[kc * 73728L]);
    out[idx] = f2b(acc);
}

// LayerNorm over D=384; input f32 (INF32=1) or bf16 (INF32=0); bf16 out (may alias in).
template<int INF32>
__global__ __launch_bounds__(256)
void ln_kernel(const void* __restrict__ xv, u16* __restrict__ ob,
               const float* __restrict__ g, const float* __restrict__ bta)
{
    const int lane = threadIdx.x & 63;
    const long r = (long)blockIdx.x * 4 + (threadIdx.x >> 6);
    float v[6]; float s = 0.f;
    #pragma unroll
    for (int i = 0; i < 6; i++){
        const int c = lane + i * 64;
        v[i] = INF32 ? ((const float*)xv)[r * 384 + c]
                     : b2f(((const u16*)xv)[r * 384 + c]);
        s += v[i];
    }
    #pragma unroll
    for (int off = 32; off; off >>= 1) s += __shfl_xor(s, off);
    const float mu = s * (1.0f/384.0f);
    float q = 0.f;
    #pragma unroll
    for (int i = 0; i < 6; i++){ float d = v[i] - mu; q += d*d; }
    #pragma unroll
    for (int off = 32; off; off >>= 1) q += __shfl_xor(q, off);
    const float inv = rsqrtf(q * (1.0f/384.0f) + 1e-5f);
    #pragma unroll
    for (int i = 0; i < 6; i++){
        const int c = lane + i*64;
        ob[r * 384 + c] = f2b((v[i] - mu) * inv * g[c] + bta[c]);
    }
}

// Dn[r] = dot(qp_bf16[r,:192], kpsum[r/T,:192])
__global__ __launch_bounds__(256)
void dn_kernel(const u16* __restrict__ qp, const float* __restrict__ kpsum,
               float* __restrict__ Dn, int T)
{
    const int lane = threadIdx.x & 63;
    const long r = (long)blockIdx.x * 4 + (threadIdx.x >> 6);
    const int b = (int)(r / T);
    const u16* qr = qp + r * 192;
    const float* ks = kpsum + (long)b * 192;
    float s = 0.f;
    #pragma unroll
    for (int i = 0; i < 3; i++){ const int m = lane + i*64; s += b2f(qr[m]) * ks[m]; }
    #pragma unroll
    for (int off = 32; off; off >>= 1) s += __shfl_xor(s, off);
    if (lane == 0) Dn[r] = s;
}

// kpsum[bl][m] = sum_t kpT[m][bl*T + t]
__global__ __launch_bounds__(256)
void kpsum2_kernel(const u16* __restrict__ kpT, float* __restrict__ kpsum, long Mc, int T)
{
    const int lane = threadIdx.x & 63;
    const int gw = blockIdx.x * 4 + (threadIdx.x >> 6);
    const int m = gw % 192, bl = gw / 192;
    const u16* row = kpT + (long)m * Mc + (long)bl * T;
    float s = 0.f;
    for (int i = lane; i < T; i += 64) s += b2f(row[i]);
    #pragma unroll
    for (int off = 32; off; off >>= 1) s += __shfl_xor(s, off);
    if (lane == 0) kpsum[bl * 192 + m] = s;
}

__global__ __launch_bounds__(256)
void zero_kernel(float* __restrict__ p, long n)
{
    long i = (long)blockIdx.x * 256 + threadIdx.x;
    long stride = (long)gridDim.x * 256;
    for (; i < n; i += stride) p[i] = 0.f;
}

// concat(in1,in2) row-major -> bf16 [Mc][768]
__global__ __launch_bounds__(256)
void ca_kernel(const float* __restrict__ i1, const float* __restrict__ i2,
               u16* __restrict__ a0, long nquad)
{
    long idx = (long)blockIdx.x * 256 + threadIdx.x;
    if (idx >= nquad) return;
    const long r = idx / 192;
    const int  c0 = (int)(idx % 192) * 4;
    const float* src = (c0 < 384) ? &i1[r * 384 + c0] : &i2[r * 384 + (c0 - 384)];
    float4 v = *(const float4*)src;
    u32 w0 = (u32)f2b(v.x) | ((u32)f2b(v.y) << 16);
    u32 w1 = (u32)f2b(v.z) | ((u32)f2b(v.w) << 16);
    *(uint2*)&a0[r * 768 + c0] = make_uint2(w0, w1);
}

// wt[n*K + k] = bf16(w[k*N + n])
__global__ __launch_bounds__(256)
void wt_kernel(const float* __restrict__ w, u16* __restrict__ wt, int K, int N, long total)
{
    long idx = (long)blockIdx.x * 256 + threadIdx.x;
    if (idx >= total) return;
    const long n = idx / K, k = idx - n * K;
    wt[idx] = f2b(w[k * N + n]);
}

// flat f32 -> bf16
__global__ __launch_bounds__(256)
void cvt_kernel(const float* __restrict__ s, u16* __restrict__ d, long n4)
{
    long idx = (long)blockIdx.x * 256 + threadIdx.x;
    if (idx >= n4) return;
    float4 v = *(const float4*)&s[idx * 4];
    u32 w0 = (u32)f2b(v.x) | ((u32)f2b(v.y) << 16);
    u32 w1 = (u32)f2b(v.z) | ((u32)f2b(v.w) << 16);
    *(uint2*)&d[idx * 4] = make_uint2(w0, w1);
}

extern "C" void kernel_launch(void* const* d_in, const int* in_sizes, int n_in,
                              void* d_out, int out_size, void* d_ws, size_t ws_size,
                              hipStream_t stream)
{
    const long T = 3136;
    const float prm_scale = 0.07216878364870322f;  // 1/sqrt(192)

    const float* in1    = (const float*)d_in[0];
    const float* in2    = (const float*)d_in[1];
    const float* W1     = (const float*)d_in[2];
    const float* b1     = (const float*)d_in[3];
    const float* W2     = (const float*)d_in[4];
    const float* b2     = (const float*)d_in[5];
    const float* kqv_w  = (const float*)d_in[6];
    const float* kqv_b  = (const float*)d_in[7];
    const float* proj_w = (const float*)d_in[8];
    const float* proj_b = (const float*)d_in[9];
    const float* ln1_g  = (const float*)d_in[10];
    const float* ln1_b  = (const float*)d_in[11];
    const float* ln2_g  = (const float*)d_in[12];
    const float* ln2_b  = (const float*)d_in[13];
    const float* mlp_w1 = (const float*)d_in[14];
    const float* mlp_b1 = (const float*)d_in[15];
    const float* mlp_w2 = (const float*)d_in[16];
    const float* mlp_b2 = (const float*)d_in[17];
    const float* w_prm  = (const float*)d_in[18];
    float* out = (float*)d_out;

    char* p = (char*)d_ws;
    auto alloc = [&](long bytes)->char*{ char* r = p; p += (bytes + 255) & ~255L; return r; };

    // chunk-invariant bf16 weights
    u16* w1t   = (u16*)alloc(294912L * 2);
    u16* w2t   = (u16*)alloc(147456L * 2);
    u16* kqvt  = (u16*)alloc(442368L * 2);
    u16* prjt  = (u16*)alloc(147456L * 2);
    u16* m1t   = (u16*)alloc(147456L * 2);
    u16* m2t   = (u16*)alloc(147456L * 2);
    u16* wprmb = (u16*)alloc(256L * 384 * 2);
    char* chunkBase = p;

    // per-batch ws bytes (same as round 14; ybf aliases vT):
    const long perBatch = 2368L * T * 2 + T * 4
                        + 192L * 4 + 7L * 73728 * 2 + 73728L * 2;
    const long fixed = (long)(chunkBase - (char*)d_ws) + (1L << 20);
    int nb = 2;
    for (int cand = 16; cand >= 2; cand >>= 1){
        if (fixed + (long)cand * perBatch + 128L * 1024 <= (long)ws_size){ nb = cand; break; }
    }

    const dim3 blk(256);

    wt_kernel<<<dim3((294912 + 255) / 256), blk, 0, stream>>>(W1, w1t, 768, 384, 294912);
    wt_kernel<<<dim3((147456 + 255) / 256), blk, 0, stream>>>(W2, w2t, 384, 384, 147456);
    wt_kernel<<<dim3((442368 + 255) / 256), blk, 0, stream>>>(kqv_w, kqvt, 384, 1152, 442368);
    wt_kernel<<<dim3((147456 + 255) / 256), blk, 0, stream>>>(proj_w, prjt, 384, 384, 147456);
    wt_kernel<<<dim3((147456 + 255) / 256), blk, 0, stream>>>(mlp_w1, m1t, 384, 384, 147456);
    wt_kernel<<<dim3((147456 + 255) / 256), blk, 0, stream>>>(mlp_w2, m2t, 384, 384, 147456);
    zero_kernel<<<dim3(64), blk, 0, stream>>>((float*)wprmb, 256L * 384 / 2);
    cvt_kernel<<<dim3((18432 + 255) / 256), blk, 0, stream>>>(w_prm, wprmb, 18432);

    for (int b0 = 0; b0 < 16; b0 += nb){
        const long Mc = (long)nb * T;
        const int  gy128 = (int)(Mc / 128);
        const float* i1 = in1 + (long)b0 * T * 384;
        const float* i2 = in2 + (long)b0 * T * 384;
        float* outc = out + (long)b0 * T * 384;

        p = chunkBase;
        u16*  big   = (u16*)alloc(Mc * 1152 * 2);   // a0(768)+h1(tail) -> kqvb -> mlp hidden
        u16*  xb    = (u16*)alloc(Mc * 384 * 2);    // x -> xn -> t_att -> z
        u16*  qpb   = (u16*)alloc(Mc * 192 * 2);    // qp (followed by allocs: OOB pad)
        u16*  vT    = (u16*)alloc(384L * Mc * 2);   // v^T ; later y bf16
        u16*  kpT   = (u16*)alloc(256L * Mc * 2);   // kp^T (padded rows)
        float* Dn   = (float*)alloc(Mc * 4);
        float* kpsum= (float*)alloc((long)nb * 192 * 4);
        u16*  kptvA = (u16*)alloc((long)nb * 7 * 73728 * 2);   // bf16 split-K slices
        u16*  kptvb = (u16*)alloc((long)nb * 73728 * 2);
        (void)alloc(128L * 1024);

        u16* a0   = big;                      // [Mc][768]
        u16* h1   = big + Mc * 768;           // [Mc][384] (tail of big)
        u16* kqvb = big;                      // [Mc][1152] after a0/h1 dead
        u16* hbuf = big;                      // [Mc][384] after kqvb dead
        u16* ybf  = vT;                       // [Mc][384] after vT dead (post-kptv)

        // 0) a0 = bf16(concat)
        {
            long nq = Mc * 192;
            ca_kernel<<<dim3((unsigned)((nq + 255) / 256)), blk, 0, stream>>>(i1, i2, a0, nq);
        }
        // 1) h1 = GELU(a0 @ W1t^T + b1) -> big tail
        gemm_bf16<1,0,0><<<dim3(3, gy128, 1), blk, 0, stream>>>(
            a0, 768, w1t, 768, h1, 384, b1, nullptr, nullptr, 0,
            (int)Mc, 384, 768, 1, 0,0,0,0, 0.f);
        // 2) x = h1 @ W2t^T + b2 -> xb [bf16]
        gemm_bf16<0,0,0><<<dim3(3, gy128, 1), blk, 0, stream>>>(
            h1, 384, w2t, 384, xb, 384, b2, nullptr, nullptr, 0,
            (int)Mc, 384, 384, 1, 0,0,0,0, 0.f);
        // 3) LN1 in-place: xn -> xb
        ln_kernel<0><<<dim3((unsigned)(Mc / 4)), blk, 0, stream>>>(xb, xb, ln1_g, ln1_b);
        // 4) kqv = xn @ kqvt^T + kqv_b -> big [N=1152]
        gemm_bf16<0,0,0><<<dim3(9, gy128, 1), blk, 0, stream>>>(
            xb, 384, kqvt, 384, kqvb, 1152, kqv_b, nullptr, nullptr, 0,
            (int)Mc, 1152, 384, 1, 0,0,0,0, 0.f);
        // 5) FAVOR dual: z=0 kpT (transposed), z=1 qp (row); xd in-GEMM
        gemm_bf16<10,0,1><<<dim3(2, gy128, 2), blk, 0, stream>>>(
            kqvb, 1152, wprmb, 384, kpT, (int)Mc, nullptr, nullptr, qpb, 192,
            (int)Mc, 192, 384, 1, 384, 0, 0, 0, prm_scale);
        // 6) kpsum from kpT rows
        kpsum2_kernel<<<dim3(nb * 48), blk, 0, stream>>>(kpT, kpsum, Mc, (int)T);
        // 7) vT = transpose of v
        trb_kernel<<<dim3(6, (unsigned)(Mc / 64)), blk, 0, stream>>>(kqvb + 768, 1152, vT, Mc);
        // 8) kptv: [384][192] = vT(b) @ kpT(b)^T, split-K=7 bf16 slices ; reduce
        gemm_bf16<8,0,1><<<dim3(2, 3, nb * 7), blk, 0, stream>>>(
            vT, (int)Mc, kpT, (int)Mc, kptvA, 192, nullptr, nullptr, nullptr, 0,
            384, 192, 3136, 7, 3136, 3136, 73728, 0, 0.f);
        kred_kernel<<<dim3((unsigned)((long)nb * 73728 / 256)), blk, 0, stream>>>(
            kptvA, kptvb, (long)nb * 73728);
        // 9) Dn
        dn_kernel<<<dim3((unsigned)(Mc / 4)), blk, 0, stream>>>(qpb, kpsum, Dn, (int)T);
        // 10) t_att = (qp @ kptv^T)/(Dn+1e-8) -> xb
        gemm_bf16<3,1,0><<<dim3(3, 25, nb), blk, 0, stream>>>(
            qpb, 192, kptvb, 192, xb, 384, nullptr, Dn, nullptr, 0,
            (int)T, 384, 192, 1, T*192, 73728, T*384, T, 0.f);
        // 11) y = t_att @ proj + proj_b + v(bf16) -> ybf [bf16] (vT dead)
        gemm_bf16<11,0,0><<<dim3(3, gy128, 1), blk, 0, stream>>>(
            xb, 384, prjt, 384, ybf, 384, proj_b, nullptr, kqvb + 768, 1152,
            (int)Mc, 384, 384, 1, 0,0,0,0, 0.f);
        // 12) LN2 (bf16 in): z -> xb
        ln_kernel<0><<<dim3((unsigned)(Mc / 4)), blk, 0, stream>>>(ybf, xb, ln2_g, ln2_b);
        // 13) h = GELU(z @ mlp1 + b) -> hbuf (big; kqv dead)
        gemm_bf16<1,0,0><<<dim3(3, gy128, 1), blk, 0, stream>>>(
            xb, 384, m1t, 384, hbuf, 384, mlp_b1, nullptr, nullptr, 0,
            (int)Mc, 384, 384, 1, 0,0,0,0, 0.f);
        // 14) out = h @ mlp2 + b + y(bf16)  [f32 direct scatter]
        gemm_bf16<9,0,0><<<dim3(3, gy128, 1), blk, 0, stream>>>(
            hbuf, 384, m2t, 384, outc, 384, mlp_b2, nullptr, ybf, 384,
            (int)Mc, 384, 384, 1, 0,0,0,0, 0.f);
    }
}